// Round 1
// baseline (4581.008 us; speedup 1.0000x reference)
//
#include <hip/hip_runtime.h>
#include <math.h>
#include <float.h>
#include <limits.h>

#define BB 64        // batch
#define HID 768
#define VOCAB 30000
#define NG 3072      // 4*HID
#define TSTEPS 32
#define PBLK 469     // ceil(30000/64)

// ---------------------------------------------------------------------------
// Closed-form head: logits_closed = relu(feat @ c1_W.T + c1_b) @ c2_W.T + c2_b
// One block per batch row. Wave-per-hidden-row dot (lanes over k), then LDS
// reduce for the 2 outputs.
// ---------------------------------------------------------------------------
__global__ __launch_bounds__(256) void kclosed(
    const float* __restrict__ feat, const float* __restrict__ c1W,
    const float* __restrict__ c1b, const float* __restrict__ c2W,
    const float* __restrict__ c2b, float* __restrict__ out)
{
    const int b = blockIdx.x;
    const int tid = threadIdx.x;
    const int wave = tid >> 6, lane = tid & 63;
    __shared__ float hid[512];
    __shared__ float red[2][256];

    // feat row chunks into registers: lane l holds f[l*4+256j .. +3]
    float4 fr[3];
    const float4* frow = (const float4*)(feat + (size_t)b * HID);
    #pragma unroll
    for (int j = 0; j < 3; j++) fr[j] = frow[lane + 64 * j];

    for (int r = wave; r < 512; r += 4) {
        const float4* w = (const float4*)(c1W + (size_t)r * HID);
        float s = 0.f;
        #pragma unroll
        for (int j = 0; j < 3; j++) {
            float4 wv = w[lane + 64 * j];
            s += fr[j].x * wv.x + fr[j].y * wv.y + fr[j].z * wv.z + fr[j].w * wv.w;
        }
        #pragma unroll
        for (int o = 32; o; o >>= 1) s += __shfl_xor(s, o, 64);
        if (lane == 0) hid[r] = fmaxf(s + c1b[r], 0.f);
    }
    __syncthreads();

    float s0 = 0.f, s1 = 0.f;
    for (int r = tid; r < 512; r += 256) {
        float hv = hid[r];
        s0 += hv * c2W[r];          // c2_W row 0
        s1 += hv * c2W[512 + r];    // c2_W row 1
    }
    red[0][tid] = s0; red[1][tid] = s1;
    __syncthreads();
    for (int st = 128; st; st >>= 1) {
        if (tid < st) { red[0][tid] += red[0][tid + st]; red[1][tid] += red[1][tid + st]; }
        __syncthreads();
    }
    if (tid == 0) {
        out[b * 2 + 0] = red[0][0] + c2b[0];
        out[b * 2 + 1] = red[1][0] + c2b[1];
    }
}

// ---------------------------------------------------------------------------
// Gates GEMM (partial over K): tile M=64 (all batch rows) x N=64 gate-cols,
// K-split into 4 chunks of 384 (ks 0,1 -> x@W_ih halves; ks 2,3 -> h@W_hh).
// Fused: finalize argmax of previous step's logits partials (redundantly per
// block needing tokens) and gather x = emb[tok]. Block (0,0) writes generated.
// ---------------------------------------------------------------------------
__global__ __launch_bounds__(256) void kg1(
    int step, const float* __restrict__ pval, const int* __restrict__ pidx,
    const float* __restrict__ emb, const float* __restrict__ W_ih,
    const float* __restrict__ W_hh, const float* __restrict__ h_in,
    float* __restrict__ gpart, float* __restrict__ gen)
{
    const int tid = threadIdx.x;
    const int nc = blockIdx.x;   // 0..47 : gate-col chunk of 64
    const int ks = blockIdx.y;   // 0..3  : K split
    __shared__ int tok_lds[BB];
    __shared__ float as[32][68];
    __shared__ float wsl[32][68];
    __shared__ float fv[BB][4];
    __shared__ int   fi[BB][4];

    if (ks < 2) {  // only x-side blocks need tokens
        if (step == 0) {
            if (tid < BB) tok_lds[tid] = 0;
        } else {
            const int r = tid >> 2, seg = tid & 3;
            float bv = -FLT_MAX; int bi = INT_MAX;
            for (int p = seg; p < PBLK; p += 4) {
                float v = pval[r * PBLK + p]; int ix = pidx[r * PBLK + p];
                if (v > bv || (v == bv && ix < bi)) { bv = v; bi = ix; }
            }
            fv[r][seg] = bv; fi[r][seg] = bi;
            __syncthreads();
            if (tid < BB) {
                float cv = -FLT_MAX; int ci = INT_MAX;
                #pragma unroll
                for (int s = 0; s < 4; s++) {
                    float v = fv[tid][s]; int ix = fi[tid][s];
                    if (v > cv || (v == cv && ix < ci)) { cv = v; ci = ix; }
                }
                tok_lds[tid] = ci;
                if (nc == 0) gen[tid * TSTEPS + step - 1] = (float)ci;
            }
        }
    }
    __syncthreads();

    const int ty = tid >> 4, tx = tid & 15;  // rows ty*4.., cols tx*4..
    float acc[4][4] = {};

    for (int k0 = 0; k0 < 384; k0 += 32) {
        for (int i = tid; i < 512; i += 256) {   // A: 64 rows x 32 k
            int r = i >> 3, kq = i & 7;
            const float* base = (ks < 2)
                ? (emb + (size_t)tok_lds[r] * HID + ks * 384)
                : (h_in + (size_t)r * HID + (ks - 2) * 384);
            float4 v = *(const float4*)(base + k0 + kq * 4);
            as[kq*4+0][r] = v.x; as[kq*4+1][r] = v.y;
            as[kq*4+2][r] = v.z; as[kq*4+3][r] = v.w;
        }
        for (int i = tid; i < 512; i += 256) {   // W: 64 cols x 32 k
            int c = i >> 3, kq = i & 7;
            int gcol = nc * 64 + c;
            const float* wb = (ks < 2)
                ? (W_ih + (size_t)gcol * HID + ks * 384)
                : (W_hh + (size_t)gcol * HID + (ks - 2) * 384);
            float4 v = *(const float4*)(wb + k0 + kq * 4);
            wsl[kq*4+0][c] = v.x; wsl[kq*4+1][c] = v.y;
            wsl[kq*4+2][c] = v.z; wsl[kq*4+3][c] = v.w;
        }
        __syncthreads();
        #pragma unroll
        for (int kk = 0; kk < 32; kk++) {
            float4 av = *(const float4*)&as[kk][ty * 4];
            float4 wv = *(const float4*)&wsl[kk][tx * 4];
            acc[0][0] += av.x*wv.x; acc[0][1] += av.x*wv.y; acc[0][2] += av.x*wv.z; acc[0][3] += av.x*wv.w;
            acc[1][0] += av.y*wv.x; acc[1][1] += av.y*wv.y; acc[1][2] += av.y*wv.z; acc[1][3] += av.y*wv.w;
            acc[2][0] += av.z*wv.x; acc[2][1] += av.z*wv.y; acc[2][2] += av.z*wv.z; acc[2][3] += av.z*wv.w;
            acc[3][0] += av.w*wv.x; acc[3][1] += av.w*wv.y; acc[3][2] += av.w*wv.z; acc[3][3] += av.w*wv.w;
        }
        __syncthreads();
    }
    #pragma unroll
    for (int i = 0; i < 4; i++) {
        float4 v = make_float4(acc[i][0], acc[i][1], acc[i][2], acc[i][3]);
        *(float4*)(gpart + ((size_t)ks * BB + ty * 4 + i) * NG + nc * 64 + tx * 4) = v;
    }
}

// ---------------------------------------------------------------------------
// Cell: sum the 4 K-partials (deterministic order), add biases, LSTM update.
// ---------------------------------------------------------------------------
__global__ __launch_bounds__(256) void kc(
    int step, const float* __restrict__ gpart, const float* __restrict__ b_ih,
    const float* __restrict__ b_hh, float* __restrict__ cbuf, float* __restrict__ h_out)
{
    int idx = blockIdx.x * 256 + threadIdx.x;   // < 64*768
    int b = idx / HID, j = idx % HID;
    float g4[4];
    #pragma unroll
    for (int g = 0; g < 4; g++) {
        int col = g * HID + j;
        float s = b_ih[col] + b_hh[col];
        #pragma unroll
        for (int ksd = 0; ksd < 4; ksd++)
            s += gpart[((size_t)ksd * BB + b) * NG + col];
        g4[g] = s;
    }
    float cprev = (step == 0) ? 0.f : cbuf[idx];
    float ig = 1.f / (1.f + expf(-g4[0]));
    float fg = 1.f / (1.f + expf(-g4[1]));
    float gg = tanhf(g4[2]);
    float og = 1.f / (1.f + expf(-g4[3]));
    float cn = fg * cprev + ig * gg;
    float hn = og * tanhf(cn);
    cbuf[idx] = cn;
    h_out[idx] = hn;
}

// ---------------------------------------------------------------------------
// Logits GEMM + per-block argmax partial: tile M=64 (all rows) x N=64 cols,
// K chunked by 32 through LDS (padded to kill bank conflicts).
// ---------------------------------------------------------------------------
__global__ __launch_bounds__(256) void kb(
    const float* __restrict__ h, const float* __restrict__ outW,
    const float* __restrict__ outb, float* __restrict__ pval, int* __restrict__ pidx)
{
    __shared__ float hs[32][68];
    __shared__ float wsl[32][68];
    __shared__ float rv[BB][16];
    __shared__ int   ri[BB][16];
    const int tid = threadIdx.x;
    const int cb = blockIdx.x;
    const int c0 = cb * 64;
    const int ty = tid >> 4, tx = tid & 15;
    float acc[4][4] = {};

    for (int k0 = 0; k0 < HID; k0 += 32) {
        for (int i = tid; i < 512; i += 256) {
            int r = i >> 3, kq = i & 7;
            float4 v = *(const float4*)(h + (size_t)r * HID + k0 + kq * 4);
            hs[kq*4+0][r] = v.x; hs[kq*4+1][r] = v.y;
            hs[kq*4+2][r] = v.z; hs[kq*4+3][r] = v.w;
        }
        for (int i = tid; i < 512; i += 256) {
            int c = i >> 3, kq = i & 7;
            int gc = c0 + c;
            float4 v = make_float4(0.f, 0.f, 0.f, 0.f);
            if (gc < VOCAB) v = *(const float4*)(outW + (size_t)gc * HID + k0 + kq * 4);
            wsl[kq*4+0][c] = v.x; wsl[kq*4+1][c] = v.y;
            wsl[kq*4+2][c] = v.z; wsl[kq*4+3][c] = v.w;
        }
        __syncthreads();
        #pragma unroll
        for (int kk = 0; kk < 32; kk++) {
            float4 av = *(const float4*)&hs[kk][ty * 4];
            float4 wv = *(const float4*)&wsl[kk][tx * 4];
            acc[0][0] += av.x*wv.x; acc[0][1] += av.x*wv.y; acc[0][2] += av.x*wv.z; acc[0][3] += av.x*wv.w;
            acc[1][0] += av.y*wv.x; acc[1][1] += av.y*wv.y; acc[1][2] += av.y*wv.z; acc[1][3] += av.y*wv.w;
            acc[2][0] += av.z*wv.x; acc[2][1] += av.z*wv.y; acc[2][2] += av.z*wv.z; acc[2][3] += av.z*wv.w;
            acc[3][0] += av.w*wv.x; acc[3][1] += av.w*wv.y; acc[3][2] += av.w*wv.z; acc[3][3] += av.w*wv.w;
        }
        __syncthreads();
    }

    // epilogue: + out_b, then first-occurrence argmax over this block's cols
    #pragma unroll
    for (int i = 0; i < 4; i++) {
        float bv = -FLT_MAX; int bi = INT_MAX;
        #pragma unroll
        for (int j = 0; j < 4; j++) {
            int c = c0 + tx * 4 + j;
            if (c < VOCAB) {
                float v = acc[i][j] + outb[c];
                if (v > bv || (v == bv && c < bi)) { bv = v; bi = c; }
            }
        }
        rv[ty * 4 + i][tx] = bv; ri[ty * 4 + i][tx] = bi;
    }
    __syncthreads();
    if (tid < BB) {
        float bv = -FLT_MAX; int bi = INT_MAX;
        #pragma unroll
        for (int x = 0; x < 16; x++) {
            float v = rv[tid][x]; int ix = ri[tid][x];
            if (v > bv || (v == bv && ix < bi)) { bv = v; bi = ix; }
        }
        pval[tid * PBLK + cb] = bv;
        pidx[tid * PBLK + cb] = bi;
    }
}

// ---------------------------------------------------------------------------
// Final token (step 31) from the last partials.
// ---------------------------------------------------------------------------
__global__ __launch_bounds__(64) void kflast(
    const float* __restrict__ pval, const int* __restrict__ pidx, float* __restrict__ gen)
{
    const int b = blockIdx.x, tid = threadIdx.x;
    float bv = -FLT_MAX; int bi = INT_MAX;
    for (int p = tid; p < PBLK; p += 64) {
        float v = pval[b * PBLK + p]; int ix = pidx[b * PBLK + p];
        if (v > bv || (v == bv && ix < bi)) { bv = v; bi = ix; }
    }
    #pragma unroll
    for (int o = 32; o; o >>= 1) {
        float ov = __shfl_xor(bv, o, 64);
        int   oi = __shfl_xor(bi, o, 64);
        if (ov > bv || (ov == bv && oi < bi)) { bv = ov; bi = oi; }
    }
    if (tid == 0) gen[b * TSTEPS + 31] = (float)bi;
}

// ---------------------------------------------------------------------------
extern "C" void kernel_launch(void* const* d_in, const int* in_sizes, int n_in,
                              void* d_out, int out_size, void* d_ws, size_t ws_size,
                              hipStream_t stream)
{
    const float* feat = (const float*)d_in[0];
    const float* emb  = (const float*)d_in[1];
    const float* W_ih = (const float*)d_in[2];
    const float* W_hh = (const float*)d_in[3];
    const float* b_ih = (const float*)d_in[4];
    const float* b_hh = (const float*)d_in[5];
    const float* outW = (const float*)d_in[6];
    const float* outb = (const float*)d_in[7];
    const float* c1W  = (const float*)d_in[8];
    const float* c1b  = (const float*)d_in[9];
    const float* c2W  = (const float*)d_in[10];
    const float* c2b  = (const float*)d_in[11];
    (void)in_sizes; (void)n_in; (void)out_size; (void)ws_size;

    float* out = (float*)d_out;
    float* gen = out + BB * 2;                 // generated (64x32), as floats

    float* ws    = (float*)d_ws;
    float* hbuf  = ws;                          // 2 * 64*768
    float* cbuf  = hbuf + 2 * BB * HID;         // 64*768
    float* gpart = cbuf + BB * HID;             // 4 * 64 * 3072
    float* pval  = gpart + 4 * (size_t)BB * NG; // 64*469
    int*   pidx  = (int*)(pval + BB * PBLK);    // 64*469

    kclosed<<<BB, 256, 0, stream>>>(feat, c1W, c1b, c2W, c2b, out);

    for (int t = 0; t < TSTEPS; t++) {
        const float* h_in = (t == 0) ? feat : (hbuf + ((t - 1) & 1) * BB * HID);
        float* h_out = hbuf + (t & 1) * BB * HID;
        kg1<<<dim3(48, 4), 256, 0, stream>>>(t, pval, pidx, emb, W_ih, W_hh, h_in, gpart, gen);
        kc<<<dim3(192), 256, 0, stream>>>(t, gpart, b_ih, b_hh, cbuf, h_out);
        kb<<<dim3(PBLK), 256, 0, stream>>>(h_out, outW, outb, pval, pidx);
    }
    kflast<<<BB, 64, 0, stream>>>(pval, pidx, gen);
}

// Round 2
// 3423.467 us; speedup vs baseline: 1.3381x; 1.3381x over previous
//
#include <hip/hip_runtime.h>
#include <math.h>
#include <float.h>
#include <limits.h>

#define BB 64        // batch
#define HID 768
#define VOCAB 30000
#define NG 3072      // 4*HID
#define TSTEPS 32
#define PBLK 469     // ceil(30000/64)

// ---------------------------------------------------------------------------
// Closed head stage 1: hid[b][r] = relu(feat[b] . c1W[r] + c1b[r]), r<512.
// grid (4, 64): x = quarter of the 512 rows, y = batch row. 256 thr = 4 waves,
// each wave 32 rows via 64-lane dot + shuffle reduce. Bit-identical to R1.
// ---------------------------------------------------------------------------
__global__ __launch_bounds__(256) void kc1(
    const float* __restrict__ feat, const float* __restrict__ c1W,
    const float* __restrict__ c1b, float* __restrict__ hid_ws)
{
    const int q = blockIdx.x, b = blockIdx.y;
    const int wave = threadIdx.x >> 6, lane = threadIdx.x & 63;
    float4 fr[3];
    const float4* frow = (const float4*)(feat + (size_t)b * HID);
    #pragma unroll
    for (int j = 0; j < 3; j++) fr[j] = frow[lane + 64 * j];

    #pragma unroll 2
    for (int rr = 0; rr < 32; rr++) {
        const int r = q * 128 + wave * 32 + rr;
        const float4* w = (const float4*)(c1W + (size_t)r * HID);
        float s = 0.f;
        #pragma unroll
        for (int j = 0; j < 3; j++) {
            float4 wv = w[lane + 64 * j];
            s += fr[j].x * wv.x + fr[j].y * wv.y + fr[j].z * wv.z + fr[j].w * wv.w;
        }
        #pragma unroll
        for (int o = 32; o; o >>= 1) s += __shfl_xor(s, o, 64);
        if (lane == 0) hid_ws[b * 512 + r] = fmaxf(s + c1b[r], 0.f);
    }
}

// Closed head stage 2: out[b][0..1] = hid[b] @ c2W.T + c2b. 64 blocks.
__global__ __launch_bounds__(256) void kc2(
    const float* __restrict__ hid_ws, const float* __restrict__ c2W,
    const float* __restrict__ c2b, float* __restrict__ out)
{
    const int b = blockIdx.x, tid = threadIdx.x;
    __shared__ float red[2][256];
    float s0 = 0.f, s1 = 0.f;
    for (int r = tid; r < 512; r += 256) {
        float hv = hid_ws[b * 512 + r];
        s0 += hv * c2W[r];
        s1 += hv * c2W[512 + r];
    }
    red[0][tid] = s0; red[1][tid] = s1;
    __syncthreads();
    for (int st = 128; st; st >>= 1) {
        if (tid < st) { red[0][tid] += red[0][tid + st]; red[1][tid] += red[1][tid + st]; }
        __syncthreads();
    }
    if (tid == 0) {
        out[b * 2 + 0] = red[0][0] + c2b[0];
        out[b * 2 + 1] = red[1][0] + c2b[1];
    }
}

// ---------------------------------------------------------------------------
// Gates GEMM partial: grid (48, 6). nc = 64-col chunk of 3072; ks = 256-k
// chunk of the concat-K 1536 (ks<3: x=emb[tok] @ W_ih; else h @ W_hh).
// BK=64 chunks with register-prefetch software pipeline.
// ---------------------------------------------------------------------------
__global__ __launch_bounds__(256) void kg1(
    int step, const int* __restrict__ tok_ws, const float* __restrict__ emb,
    const float* __restrict__ W_ih, const float* __restrict__ W_hh,
    const float* __restrict__ h_in, float* __restrict__ gpart)
{
    const int tid = threadIdx.x;
    const int nc = blockIdx.x;   // 0..47
    const int ks = blockIdx.y;   // 0..5
    __shared__ float as[64][68];
    __shared__ float wsl[64][68];
    const int ty = tid >> 4, tx = tid & 15;

    // per-thread staged (row, float4-col) pairs: i = tid + 256j
    const float* abase[4];
    const float* wbase[4];
    int c4v[4], rv_[4];
    #pragma unroll
    for (int j = 0; j < 4; j++) {
        int i = tid + 256 * j;
        int r = i >> 4, c4 = i & 15;
        rv_[j] = r; c4v[j] = c4;
        if (ks < 3) {
            int tok = (step == 0) ? 0 : tok_ws[r];
            abase[j] = emb + (size_t)tok * HID + ks * 256;
        } else {
            abase[j] = h_in + (size_t)r * HID + (ks - 3) * 256;
        }
        int gcol = nc * 64 + r;
        wbase[j] = (ks < 3) ? (W_ih + (size_t)gcol * HID + ks * 256)
                            : (W_hh + (size_t)gcol * HID + (ks - 3) * 256);
    }

    float4 pa[4], pw[4];
    #pragma unroll
    for (int j = 0; j < 4; j++) {
        pa[j] = *(const float4*)(abase[j] + c4v[j] * 4);
        pw[j] = *(const float4*)(wbase[j] + c4v[j] * 4);
    }
    #pragma unroll
    for (int j = 0; j < 4; j++) {
        int r = rv_[j], cc = c4v[j] * 4;
        as[cc+0][r] = pa[j].x; as[cc+1][r] = pa[j].y; as[cc+2][r] = pa[j].z; as[cc+3][r] = pa[j].w;
        wsl[cc+0][r] = pw[j].x; wsl[cc+1][r] = pw[j].y; wsl[cc+2][r] = pw[j].z; wsl[cc+3][r] = pw[j].w;
    }

    float acc[4][4] = {};
    for (int ch = 0; ch < 4; ch++) {
        __syncthreads();   // staged LDS visible
        if (ch < 3) {
            int off = (ch + 1) * 64;
            #pragma unroll
            for (int j = 0; j < 4; j++) {
                pa[j] = *(const float4*)(abase[j] + off + c4v[j] * 4);
                pw[j] = *(const float4*)(wbase[j] + off + c4v[j] * 4);
            }
        }
        #pragma unroll 16
        for (int kk = 0; kk < 64; kk++) {
            float4 av = *(const float4*)&as[kk][ty * 4];
            float4 wv = *(const float4*)&wsl[kk][tx * 4];
            acc[0][0] += av.x*wv.x; acc[0][1] += av.x*wv.y; acc[0][2] += av.x*wv.z; acc[0][3] += av.x*wv.w;
            acc[1][0] += av.y*wv.x; acc[1][1] += av.y*wv.y; acc[1][2] += av.y*wv.z; acc[1][3] += av.y*wv.w;
            acc[2][0] += av.z*wv.x; acc[2][1] += av.z*wv.y; acc[2][2] += av.z*wv.z; acc[2][3] += av.z*wv.w;
            acc[3][0] += av.w*wv.x; acc[3][1] += av.w*wv.y; acc[3][2] += av.w*wv.z; acc[3][3] += av.w*wv.w;
        }
        __syncthreads();   // done reading this chunk
        if (ch < 3) {
            #pragma unroll
            for (int j = 0; j < 4; j++) {
                int r = rv_[j], cc = c4v[j] * 4;
                as[cc+0][r] = pa[j].x; as[cc+1][r] = pa[j].y; as[cc+2][r] = pa[j].z; as[cc+3][r] = pa[j].w;
                wsl[cc+0][r] = pw[j].x; wsl[cc+1][r] = pw[j].y; wsl[cc+2][r] = pw[j].z; wsl[cc+3][r] = pw[j].w;
            }
        }
    }
    #pragma unroll
    for (int i = 0; i < 4; i++) {
        float4 v = make_float4(acc[i][0], acc[i][1], acc[i][2], acc[i][3]);
        *(float4*)(gpart + ((size_t)(ks * BB) + ty * 4 + i) * NG + nc * 64 + tx * 4) = v;
    }
}

// ---------------------------------------------------------------------------
// Cell: sum 6 K-partials (fixed order) + biases, LSTM update.
// ---------------------------------------------------------------------------
__global__ __launch_bounds__(256) void kc(
    int step, const float* __restrict__ gpart, const float* __restrict__ b_ih,
    const float* __restrict__ b_hh, float* __restrict__ cbuf, float* __restrict__ h_out)
{
    int idx = blockIdx.x * 256 + threadIdx.x;   // < 64*768
    int b = idx / HID, j = idx % HID;
    float g4[4];
    #pragma unroll
    for (int g = 0; g < 4; g++) {
        int col = g * HID + j;
        float s = b_ih[col] + b_hh[col];
        #pragma unroll
        for (int ksd = 0; ksd < 6; ksd++)
            s += gpart[((size_t)ksd * BB + b) * NG + col];
        g4[g] = s;
    }
    float cprev = (step == 0) ? 0.f : cbuf[idx];
    float ig = 1.f / (1.f + expf(-g4[0]));
    float fg = 1.f / (1.f + expf(-g4[1]));
    float gg = tanhf(g4[2]);
    float og = 1.f / (1.f + expf(-g4[3]));
    float cn = fg * cprev + ig * gg;
    float hn = og * tanhf(cn);
    cbuf[idx] = cn;
    h_out[idx] = hn;
}

// ---------------------------------------------------------------------------
// Logits GEMM + per-block argmax partial. 469 blocks, 64x64 tile, BK=64,
// register-prefetch pipeline. Accumulation order per element = k ascending
// (bit-identical logits to R1).
// ---------------------------------------------------------------------------
__global__ __launch_bounds__(256) void kb(
    const float* __restrict__ h, const float* __restrict__ outW,
    const float* __restrict__ outb, float* __restrict__ pval, int* __restrict__ pidx)
{
    __shared__ float hs[64][68];
    __shared__ float wsl[64][68];
    __shared__ float rv[BB][16];
    __shared__ int   ri[BB][16];
    const int tid = threadIdx.x;
    const int cb = blockIdx.x;
    const int c0 = cb * 64;
    const int ty = tid >> 4, tx = tid & 15;

    const float* abase[4];
    const float* wbase[4];
    int c4v[4], rv_[4], wok[4];
    #pragma unroll
    for (int j = 0; j < 4; j++) {
        int i = tid + 256 * j;
        int r = i >> 4, c4 = i & 15;
        rv_[j] = r; c4v[j] = c4;
        abase[j] = h + (size_t)r * HID;
        int gc = c0 + r;
        wok[j] = (gc < VOCAB);
        wbase[j] = outW + (size_t)(wok[j] ? gc : 0) * HID;
    }

    float4 pa[4], pw[4];
    const float4 z4 = make_float4(0.f, 0.f, 0.f, 0.f);
    #pragma unroll
    for (int j = 0; j < 4; j++) {
        pa[j] = *(const float4*)(abase[j] + c4v[j] * 4);
        pw[j] = wok[j] ? *(const float4*)(wbase[j] + c4v[j] * 4) : z4;
    }
    #pragma unroll
    for (int j = 0; j < 4; j++) {
        int r = rv_[j], cc = c4v[j] * 4;
        hs[cc+0][r] = pa[j].x; hs[cc+1][r] = pa[j].y; hs[cc+2][r] = pa[j].z; hs[cc+3][r] = pa[j].w;
        wsl[cc+0][r] = pw[j].x; wsl[cc+1][r] = pw[j].y; wsl[cc+2][r] = pw[j].z; wsl[cc+3][r] = pw[j].w;
    }

    float acc[4][4] = {};
    for (int ch = 0; ch < 12; ch++) {
        __syncthreads();
        if (ch < 11) {
            int off = (ch + 1) * 64;
            #pragma unroll
            for (int j = 0; j < 4; j++) {
                pa[j] = *(const float4*)(abase[j] + off + c4v[j] * 4);
                pw[j] = wok[j] ? *(const float4*)(wbase[j] + off + c4v[j] * 4) : z4;
            }
        }
        #pragma unroll 16
        for (int kk = 0; kk < 64; kk++) {
            float4 av = *(const float4*)&hs[kk][ty * 4];
            float4 wv = *(const float4*)&wsl[kk][tx * 4];
            acc[0][0] += av.x*wv.x; acc[0][1] += av.x*wv.y; acc[0][2] += av.x*wv.z; acc[0][3] += av.x*wv.w;
            acc[1][0] += av.y*wv.x; acc[1][1] += av.y*wv.y; acc[1][2] += av.y*wv.z; acc[1][3] += av.y*wv.w;
            acc[2][0] += av.z*wv.x; acc[2][1] += av.z*wv.y; acc[2][2] += av.z*wv.z; acc[2][3] += av.z*wv.w;
            acc[3][0] += av.w*wv.x; acc[3][1] += av.w*wv.y; acc[3][2] += av.w*wv.z; acc[3][3] += av.w*wv.w;
        }
        __syncthreads();
        if (ch < 11) {
            #pragma unroll
            for (int j = 0; j < 4; j++) {
                int r = rv_[j], cc = c4v[j] * 4;
                hs[cc+0][r] = pa[j].x; hs[cc+1][r] = pa[j].y; hs[cc+2][r] = pa[j].z; hs[cc+3][r] = pa[j].w;
                wsl[cc+0][r] = pw[j].x; wsl[cc+1][r] = pw[j].y; wsl[cc+2][r] = pw[j].z; wsl[cc+3][r] = pw[j].w;
            }
        }
    }

    // epilogue: + out_b, first-occurrence argmax over this block's 64 cols
    #pragma unroll
    for (int i = 0; i < 4; i++) {
        float bv = -FLT_MAX; int bi = INT_MAX;
        #pragma unroll
        for (int j = 0; j < 4; j++) {
            int c = c0 + tx * 4 + j;
            if (c < VOCAB) {
                float v = acc[i][j] + outb[c];
                if (v > bv || (v == bv && c < bi)) { bv = v; bi = c; }
            }
        }
        rv[ty * 4 + i][tx] = bv; ri[ty * 4 + i][tx] = bi;
    }
    __syncthreads();
    if (tid < BB) {
        float bv = -FLT_MAX; int bi = INT_MAX;
        #pragma unroll
        for (int x = 0; x < 16; x++) {
            float v = rv[tid][x]; int ix = ri[tid][x];
            if (v > bv || (v == bv && ix < bi)) { bv = v; bi = ix; }
        }
        pval[tid * PBLK + cb] = bv;
        pidx[tid * PBLK + cb] = bi;
    }
}

// ---------------------------------------------------------------------------
// Token finalize: per batch row, reduce the 469 partials; write token + gen.
// ---------------------------------------------------------------------------
__global__ __launch_bounds__(256) void kfin(
    int step, const float* __restrict__ pval, const int* __restrict__ pidx,
    int* __restrict__ tok_ws, float* __restrict__ gen)
{
    const int b = blockIdx.x, tid = threadIdx.x;
    __shared__ float sv[256];
    __shared__ int   si[256];
    float bv = -FLT_MAX; int bi = INT_MAX;
    for (int p = tid; p < PBLK; p += 256) {
        float v = pval[b * PBLK + p]; int ix = pidx[b * PBLK + p];
        if (v > bv || (v == bv && ix < bi)) { bv = v; bi = ix; }
    }
    sv[tid] = bv; si[tid] = bi;
    __syncthreads();
    for (int st = 128; st; st >>= 1) {
        if (tid < st) {
            float v = sv[tid + st]; int ix = si[tid + st];
            if (v > sv[tid] || (v == sv[tid] && ix < si[tid])) { sv[tid] = v; si[tid] = ix; }
        }
        __syncthreads();
    }
    if (tid == 0) {
        tok_ws[b] = si[0];
        gen[b * TSTEPS + step] = (float)si[0];
    }
}

// ---------------------------------------------------------------------------
extern "C" void kernel_launch(void* const* d_in, const int* in_sizes, int n_in,
                              void* d_out, int out_size, void* d_ws, size_t ws_size,
                              hipStream_t stream)
{
    const float* feat = (const float*)d_in[0];
    const float* emb  = (const float*)d_in[1];
    const float* W_ih = (const float*)d_in[2];
    const float* W_hh = (const float*)d_in[3];
    const float* b_ih = (const float*)d_in[4];
    const float* b_hh = (const float*)d_in[5];
    const float* outW = (const float*)d_in[6];
    const float* outb = (const float*)d_in[7];
    const float* c1W  = (const float*)d_in[8];
    const float* c1b  = (const float*)d_in[9];
    const float* c2W  = (const float*)d_in[10];
    const float* c2b  = (const float*)d_in[11];
    (void)in_sizes; (void)n_in; (void)out_size; (void)ws_size;

    float* out = (float*)d_out;
    float* gen = out + BB * 2;                  // generated (64x32), as floats

    float* ws     = (float*)d_ws;
    float* hbuf   = ws;                          // 2 * 64*768
    float* cbuf   = hbuf + 2 * BB * HID;         // 64*768
    float* gpart  = cbuf + BB * HID;             // 6 * 64 * 3072
    float* pval   = gpart + 6 * (size_t)BB * NG; // 64*469
    int*   pidx   = (int*)(pval + BB * PBLK);    // 64*469
    int*   tok    = pidx + BB * PBLK;            // 64
    float* hid_ws = (float*)(tok + BB);          // 64*512

    kc1<<<dim3(4, BB), 256, 0, stream>>>(feat, c1W, c1b, hid_ws);
    kc2<<<BB, 256, 0, stream>>>(hid_ws, c2W, c2b, out);

    for (int t = 0; t < TSTEPS; t++) {
        const float* h_in = (t == 0) ? feat : (hbuf + ((t - 1) & 1) * BB * HID);
        float* h_out = hbuf + (t & 1) * BB * HID;
        kg1<<<dim3(48, 6), 256, 0, stream>>>(t, tok, emb, W_ih, W_hh, h_in, gpart);
        kc<<<dim3(192), 256, 0, stream>>>(t, gpart, b_ih, b_hh, cbuf, h_out);
        kb<<<dim3(PBLK), 256, 0, stream>>>(h_out, outW, outb, pval, pidx);
        kfin<<<BB, 256, 0, stream>>>(t, pval, pidx, tok, gen);
    }
}